// Round 8
// baseline (175.565 us; speedup 1.0000x reference)
//
#include <hip/hip_runtime.h>
#include <stdint.h>

// out[n,o] = sum_{d,i} q[n,d] x[n,i] W1[d,i,o] + (q @ b1)[n,o]
// GEMM M=4096 N=256 K=16384 (k=d*256+i), fp16 MFMA 32x32x16, fp32 accum.
// A-frag = x-frag (LDS) * q[row,d] per-lane scalar.
// R8: R7's Ph (16 MB) blew past ws_size (proven >= ~11 MB only) -> fault.
// New cut: grid 256 = 2 sgk (K halves) x 4 nq (64-col slices) x 32 mb (128
// rows). ws = Wt 8 MB + Xt 2 MB = 10 MB (proven safe). Atomic epilogue is
// only 2x out = 8 MB (~8 us at the measured ~1 us/MB HBM atomic drain).
// Waves (512 thr): 2M x 2N x 2K; K-halves merge via LDS at the end.
// x tile (64 KB) LDS-resident whole kernel; W ring 3x8 KB, 1 staging
// instr/window, raw s_barrier + s_waitcnt vmcnt(2) (prefetches in flight
// across barriers, vmcnt never 0 in the loop).

typedef _Float16 f16;
typedef f16 f16x8 __attribute__((ext_vector_type(8)));
typedef float f32x16 __attribute__((ext_vector_type(16)));

#define NROWS 4096
#define QDIM 64

__device__ __forceinline__ void gl_lds16(const void* g, void* s) {
  __builtin_amdgcn_global_load_lds(
      (const __attribute__((address_space(1))) void*)(uintptr_t)g,
      (__attribute__((address_space(3))) void*)(uint32_t)(uintptr_t)s,
      16, 0, 0);
}

// Wt: 1024 chunks of 8 KB. chunk cid = (sgk*4+nq)*128 + v, v = ic*16+dg.
//   unit u = (kw*4+s*2+h)*64 + c  (f16x8):
//   W1[k*256 + o], k = (sgk*32+dg*2+kw)*256 + ic*32 + s*16 + h*8 + j,
//                  o = nq*64 + c.
// Xt: per mb 4096 units (64 KB): u = kp*128 + row (kp = ic*4+s*2+h):
//   x[mb*128+row][kp*8+j].
// prep grid 1152: [0,512) W (2 chunks each) | [512,640) x | [640,1152) bias.
__global__ __launch_bounds__(256) void prep(const float* __restrict__ W,
                                            const float* __restrict__ X,
                                            const float* __restrict__ Q,
                                            const float* __restrict__ B1,
                                            f16* __restrict__ Wt,
                                            f16* __restrict__ Xt,
                                            float* __restrict__ out) {
  __shared__ float qs[512];
  const int b = blockIdx.x;
  const int t = threadIdx.x;
  if (b < 512) {
#pragma unroll
    for (int cc = 0; cc < 2; ++cc) {
      const int cid = (b << 1) + cc;
      const int v = cid & 127;
      const int sq = cid >> 7;
      const int sgk = sq >> 2, nq = sq & 3;
      const int ic = v >> 4, dg = v & 15;
#pragma unroll
      for (int rr = 0; rr < 2; ++rr) {
        const int u = (rr << 8) + t;
        const int c = u & 63;
        const int ks = u >> 6;               // kw*4 + s*2 + h
        const int kw = ks >> 2, s = (ks >> 1) & 1, h = ks & 1;
        const int k0 = ((sgk << 5) + (dg << 1) + kw) * 256 + (ic << 5) + (s << 4) + (h << 3);
        const int o = (nq << 6) + c;
        f16x8 hv;
#pragma unroll
        for (int j = 0; j < 8; ++j)
          hv[j] = (f16)W[(size_t)(k0 + j) * 256 + o];  // coalesced over o
        *(f16x8*)(Wt + (size_t)cid * 4096 + (size_t)u * 8) = hv;
      }
    }
  } else if (b < 640) {
    const int bb = b - 512;
    const int mb = bb >> 2, part = bb & 3;
#pragma unroll
    for (int r = 0; r < 4; ++r) {
      const int u = (part << 10) + (r << 8) + t;  // unit 0..4095
      const int row = u & 127;
      const int kp = u >> 7;
      const float* src = X + (size_t)((mb << 7) + row) * 256 + (kp << 3);
      float4 a = *(const float4*)src;
      float4 c = *(const float4*)(src + 4);
      f16x8 h;
      h[0] = (f16)a.x; h[1] = (f16)a.y; h[2] = (f16)a.z; h[3] = (f16)a.w;
      h[4] = (f16)c.x; h[5] = (f16)c.y; h[6] = (f16)c.z; h[7] = (f16)c.w;
      *(f16x8*)(Xt + (size_t)mb * 32768 + (size_t)u * 8) = h;
    }
  } else {
    // bias-init: out[n0+r][t] = sum_d q[n0+r][d] * b1[d][t]  (8 rows/block)
    const int n0 = (b - 640) << 3;
    qs[t] = Q[(size_t)n0 * QDIM + t];
    qs[256 + t] = Q[(size_t)n0 * QDIM + 256 + t];
    __syncthreads();
    float a8[8] = {0.f, 0.f, 0.f, 0.f, 0.f, 0.f, 0.f, 0.f};
#pragma unroll 4
    for (int d = 0; d < 64; ++d) {
      const float bv = B1[d * 256 + t];
#pragma unroll
      for (int r = 0; r < 8; ++r) a8[r] += qs[(r << 6) + d] * bv;
    }
#pragma unroll
    for (int r = 0; r < 8; ++r) out[(size_t)(n0 + r) * 256 + t] = a8[r];
  }
}

// ---- main GEMM: 256 blocks = 32 mb x (2 sgk x 4 nq), 512 thr (8 waves) ----
// wave = (kw, wm, wn): rows [wm*64,+64), cols [wn*32,+32), K half kw.
// 128 windows (ic8 x dg16): chunk = {d0,d1} x 32 i  (8 KB); kw-wave takes d_kw.
__global__ __launch_bounds__(512, 1) void mlp_main(const float* __restrict__ Q,
                                                   const f16* __restrict__ Wt,
                                                   const f16* __restrict__ Xt,
                                                   float* __restrict__ out) {
  __shared__ f16 s_x[32768];      // 64 KB x tile, resident whole kernel
  __shared__ f16 s_w3[3][4096];   // W ring: 3 x 8 KB (depth-2 prefetch)

  const int bid = blockIdx.x;
  const int sq = bid & 7;         // (sgk,nq) -> XCD-affine: 1 MB W slab per L2
  const int sgk = sq >> 2, nq = sq & 3;
  const int mb = bid >> 3;
  const int t = threadIdx.x;
  const int wv = t >> 6;
  const int kw = wv >> 2;         // K half
  const int wm = (wv >> 1) & 1;   // M half (64 rows)
  const int wn = wv & 1;          // N half (32 cols)
  const int l = t & 63;
  const int l31 = l & 31;
  const int hf = l >> 5;

  const char* wg = (const char*)Wt + (size_t)sq * 128 * 8192;
  const char* xg = (const char*)Xt + (size_t)mb * 65536;

  // prologue: x tile (8 instr) + W chunks 0,1 (1 instr each)
#pragma unroll
  for (int i = 0; i < 8; ++i) {
    const int off = (i << 13) + (t << 4);
    gl_lds16(xg + off, (char*)s_x + off);
  }
  gl_lds16(wg + (t << 4), (char*)s_w3[0] + (t << 4));
  gl_lds16(wg + 8192 + (t << 4), (char*)s_w3[1] + (t << 4));

  // q scalars: qr[mt][dg] = q[row][sgk*32 + dg*2 + kw], row = mb*128+wm*64+mt*32+l31
  f16 qr[2][16];
#pragma unroll
  for (int mt = 0; mt < 2; ++mt) {
    const float* qp = Q + (size_t)((mb << 7) + (wm << 6) + (mt << 5) + l31) * QDIM + (sgk << 5);
#pragma unroll
    for (int j = 0; j < 8; ++j) {
      float4 g = *(const float4*)(qp + (j << 2));
      qr[mt][2 * j]     = (f16)(kw ? g.y : g.x);
      qr[mt][2 * j + 1] = (f16)(kw ? g.w : g.z);
    }
  }

  f32x16 acc[2];
#pragma unroll
  for (int a = 0; a < 2; ++a)
#pragma unroll
    for (int r = 0; r < 16; ++r) acc[a][r] = 0.f;

  asm volatile("s_waitcnt vmcnt(0)\n\ts_barrier" ::: "memory");

  // W frag byte offset (s varies): ((kw*4 + s*2 + hf)*64 + wn*32 + l31)*16
  const int wfl = (kw << 12) + (hf << 10) + (wn << 9) + (l31 << 4);

  for (int ic = 0; ic < 8; ++ic) {
    f16x8 xf[2][2];  // [s][mt], reused across 16 dg windows
#pragma unroll
    for (int s = 0; s < 2; ++s)
#pragma unroll
      for (int mt = 0; mt < 2; ++mt)
        xf[s][mt] = *(const f16x8*)((const char*)s_x +
            ((((ic << 2) + (s << 1) + hf) << 7) + (wm << 6) + (mt << 5) + l31) * 16);
#pragma unroll 4
    for (int dg = 0; dg < 16; ++dg) {
      const int v = (ic << 4) + dg;
      const int c2 = (v + 2) & 127;   // wrap: harmless redundant re-stage
      gl_lds16(wg + ((size_t)c2 << 13) + (t << 4),
               (char*)s_w3[(v + 2) % 3] + (t << 4));
      const char* wb = (const char*)s_w3[v % 3];
#pragma unroll
      for (int s = 0; s < 2; ++s) {
        const f16x8 wf = *(const f16x8*)(wb + wfl + (s << 11));
#pragma unroll
        for (int mt = 0; mt < 2; ++mt) {
          const f16x8 a = xf[s][mt] * qr[mt][dg];
          acc[mt] = __builtin_amdgcn_mfma_f32_32x32x16_f16(a, wf, acc[mt], 0, 0, 0);
        }
      }
      asm volatile("s_waitcnt vmcnt(2)\n\ts_barrier" ::: "memory");
    }
  }

  asm volatile("s_waitcnt vmcnt(0)" ::: "memory");  // drain stray prefetches
  __syncthreads();

  // merge K halves: kw1 waves dump acc to LDS (over s_x), kw0 waves add.
  float* sp = (float*)s_x;
  const int wq = (wm << 1) + wn;  // 0..3
  if (kw == 1) {
#pragma unroll
    for (int mt = 0; mt < 2; ++mt)
#pragma unroll
      for (int r = 0; r < 16; ++r)
        sp[(wq << 11) + (((mt << 4) + r) << 6) + l] = acc[mt][r];
  }
  __syncthreads();
  if (kw == 0) {
#pragma unroll
    for (int mt = 0; mt < 2; ++mt)
#pragma unroll
      for (int r = 0; r < 16; ++r)
        acc[mt][r] += sp[(wq << 11) + (((mt << 4) + r) << 6) + l];
    // atomic split-K(=2 over sgk) accumulate onto bias-initialized out.
    // C/D (32x32): col = lane&31, row = (reg&3) + 8*(reg>>2) + 4*(lane>>5)
#pragma unroll
    for (int mt = 0; mt < 2; ++mt)
#pragma unroll
      for (int r = 0; r < 16; ++r) {
        const int row = (mb << 7) + (wm << 6) + (mt << 5) +
                        (r & 3) + ((r >> 2) << 3) + (hf << 2);
        const int col = (nq << 6) + (wn << 5) + l31;
        atomicAdd(out + (size_t)row * 256 + col, acc[mt][r]);
      }
  }
}

extern "C" void kernel_launch(void* const* d_in, const int* in_sizes, int n_in,
                              void* d_out, int out_size, void* d_ws, size_t ws_size,
                              hipStream_t stream) {
  (void)in_sizes; (void)n_in; (void)out_size; (void)ws_size;
  const float* x  = (const float*)d_in[0];   // [4096,256]
  const float* q  = (const float*)d_in[1];   // [4096,64]
  const float* W1 = (const float*)d_in[2];   // [64,256,256]
  const float* b1 = (const float*)d_in[3];   // [64,256]
  float* out = (float*)d_out;                // [4096,256] fp32

  // ws: Wt 1024 x 8 KB = 8 MB | Xt 32 x 64 KB = 2 MB   (10 MB total — proven safe)
  f16* Wt = (f16*)d_ws;
  f16* Xt = (f16*)((char*)d_ws + (size_t)1024 * 8192);

  prep<<<1152, 256, 0, stream>>>(W1, x, q, b1, Wt, Xt, out);
  mlp_main<<<256, 512, 0, stream>>>(q, Wt, Xt, out);
}